// Round 3
// baseline (20.418 us; speedup 1.0000x reference)
//
#include <hip/hip_runtime.h>

#define BLOCK 256
#define IPT   8                  // i's per thread (8 independent acc chains)
#define TJ    32                 // j-chunk per block
#define ITILE (BLOCK * IPT)      // 2048 i's per block

__global__ __launch_bounds__(BLOCK) void prl_pairs(
    const float* __restrict__ pred,
    const int*   __restrict__ targ,
    int n, float* __restrict__ partials)
{
    __shared__ float2 sj[TJ];           // x = 1 - pred[j], y = bitcast(targ[j])
    __shared__ float  wsum[BLOCK / 64];

    const int tid = threadIdx.x;
    const int i0  = blockIdx.x * ITILE;
    const int j0  = blockIdx.y * TJ;

    float pi[IPT]; int ti[IPT]; float s[IPT];
    #pragma unroll
    for (int m = 0; m < IPT; ++m) {
        const int  i = i0 + m * BLOCK + tid;
        const bool v = (i < n);
        pi[m] = v ? pred[i] : 0.0f;
        ti[m] = v ? targ[i] : 0x7fffffff;          // INT_MAX: never < tj
        s[m]  = 0.0f;
    }

    if (tid < TJ) {
        const int  j = j0 + tid;
        const bool v = (j < n);
        const float q  = v ? (1.0f - pred[j]) : 0.0f;
        const int   tj = v ? targ[j] : (int)0x80000000;  // INT_MIN: ti < tj never
        sj[tid] = make_float2(q, __int_as_float(tj));
    }
    __syncthreads();

    #pragma unroll
    for (int k = 0; k < TJ; ++k) {
        const float2 v  = sj[k];         // uniform addr -> broadcast, no conflict
        const float  q  = v.x;           // 1 - pj
        const int    tj = __float_as_int(v.y);
        #pragma unroll
        for (int m = 0; m < IPT; ++m) {
            const float h = fmaxf(pi[m] + q, 0.0f);   // max(1 - (pj - pi), 0)
            if (ti[m] < tj) s[m] += h;                // cmp + cndmask + add
        }
    }

    float st = 0.0f;
    #pragma unroll
    for (int m = 0; m < IPT; ++m) st += s[m];
    #pragma unroll
    for (int off = 32; off; off >>= 1) st += __shfl_down(st, off);

    const int wave = tid >> 6;
    if ((tid & 63) == 0) wsum[wave] = st;
    __syncthreads();
    if (tid == 0) {
        float b = 0.0f;
        #pragma unroll
        for (int w = 0; w < BLOCK / 64; ++w) b += wsum[w];
        partials[blockIdx.y * gridDim.x + blockIdx.x] = b;   // no atomics
    }
}

#define FB 1024   // final-kernel block size (16 waves)

__global__ __launch_bounds__(FB) void prl_final(
    const float* __restrict__ partials, int nparts,
    const int*   __restrict__ targ, int n, float* __restrict__ out)
{
    __shared__ int    hist[FB / 64][32];   // per-wave histograms
    __shared__ double wsum[FB / 64];
    const int tid  = threadIdx.x;
    const int wave = tid >> 6;

    #pragma unroll
    for (int b = tid; b < (FB / 64) * 32; b += FB)
        ((int*)hist)[b] = 0;
    __syncthreads();

    // histogram of targets, vectorized int4 when aligned
    if ((n & 3) == 0) {
        const int4* t4 = (const int4*)targ;
        for (int i = tid; i < (n >> 2); i += FB) {
            const int4 v = t4[i];
            atomicAdd(&hist[wave][v.x & 31], 1);
            atomicAdd(&hist[wave][v.y & 31], 1);
            atomicAdd(&hist[wave][v.z & 31], 1);
            atomicAdd(&hist[wave][v.w & 31], 1);
        }
    } else {
        for (int i = tid; i < n; i += FB)
            atomicAdd(&hist[wave][targ[i] & 31], 1);
    }

    // sum partial losses (double for determinism headroom)
    double s = 0.0;
    for (int i = tid; i < nparts; i += FB) s += (double)partials[i];
    #pragma unroll
    for (int off = 32; off; off >>= 1) s += __shfl_down(s, off);
    if ((tid & 63) == 0) wsum[wave] = s;
    __syncthreads();

    if (tid == 0) {
        double tot = 0.0;
        #pragma unroll
        for (int w = 0; w < FB / 64; ++w) tot += wsum[w];
        long long sq = 0;
        #pragma unroll
        for (int v = 0; v < 32; ++v) {
            long long h = 0;
            #pragma unroll
            for (int w = 0; w < FB / 64; ++w) h += hist[w][v];
            sq += h * h;
        }
        const long long cnt = ((long long)n * (long long)n - sq) / 2; // #(t_i<t_j)
        out[0] = (cnt > 0) ? (float)(tot / (double)cnt) : 0.0f;
    }
}

extern "C" void kernel_launch(void* const* d_in, const int* in_sizes, int n_in,
                              void* d_out, int out_size, void* d_ws, size_t ws_size,
                              hipStream_t stream) {
    const float* pred = (const float*)d_in[0];
    const int*   targ = (const int*)d_in[1];
    float*       out  = (float*)d_out;
    const int    n    = in_sizes[0];

    float* partials = (float*)d_ws;
    const int gx = (n + ITILE - 1) / ITILE;   // 4   for n=8192
    const int gy = (n + TJ - 1) / TJ;         // 256
    prl_pairs<<<dim3(gx, gy), BLOCK, 0, stream>>>(pred, targ, n, partials);
    prl_final<<<1, FB, 0, stream>>>(partials, gx * gy, targ, n, out);
}